// Round 11
// baseline (66.656 us; speedup 1.0000x reference)
//
#include <hip/hip_runtime.h>
#include <hip/hip_bf16.h>

typedef __bf16 bf16x8 __attribute__((ext_vector_type(8)));
typedef float floatx4 __attribute__((ext_vector_type(4)));

#define BM 256
#define BN 128
#define BK 64
#define A_TILE (BM * BK)   // 16384 ushorts = 32 KB
#define B_TILE (BN * BK)   // 8192 ushorts  = 16 KB
#define EPS 1e-5f

// ---------------- f32 -> bf16 conversion (vectorized, grid-stride) ----------
__global__ void cvt_f32_to_bf16(const float* __restrict__ in,
                                ushort* __restrict__ out, int n4) {
    int i = blockIdx.x * blockDim.x + threadIdx.x;
    int stride = gridDim.x * blockDim.x;
    for (; i < n4; i += stride) {
        float4 v = reinterpret_cast<const float4*>(in)[i];
        ushort4 o;
        o.x = __builtin_bit_cast(unsigned short, __float2bfloat16(v.x));
        o.y = __builtin_bit_cast(unsigned short, __float2bfloat16(v.y));
        o.z = __builtin_bit_cast(unsigned short, __float2bfloat16(v.z));
        o.w = __builtin_bit_cast(unsigned short, __float2bfloat16(v.w));
        reinterpret_cast<ushort4*>(out)[i] = o;
    }
}

// ---------------- fold BN+scale into per-column alpha/bias ------------------
__global__ void bn_fold(const float* __restrict__ scale,
                        const float* __restrict__ mean,
                        const float* __restrict__ var,
                        const float* __restrict__ gamma,
                        const float* __restrict__ beta,
                        float* __restrict__ alpha,
                        float* __restrict__ bias, int n) {
    int i = blockIdx.x * blockDim.x + threadIdx.x;
    if (i < n) {
        float rs = rsqrtf(var[i] + EPS);
        float g = gamma[i] * rs;
        alpha[i] = scale[i] * g;
        bias[i]  = beta[i] - mean[i] * g;
    }
}

__device__ __forceinline__ void gload_lds16(const ushort* g, ushort* l) {
    __builtin_amdgcn_global_load_lds(
        (const __attribute__((address_space(1))) void*)g,
        (__attribute__((address_space(3))) void*)l, 16, 0, 0);
}

// ---- bf16 MFMA GEMM: 256x128, 8 waves of 64x64, BK=64, overlap pipeline ----
// C[m][n] = sum_k A[m][k]*B[n][k]; epilogue C = C*alpha[n] + bias[n].
//
// R9 post-mortem: {read subtile -> barrier -> MFMA same subtile} serializes
// LDS-read time (~1500 cyc/tile) and MFMA (~2065): measured 3570 cyc/tile.
// R10: fat waves fixed the ratio but at 1 wave/SIMD -> worse. This round:
// keep 8 waves, make each MFMA cluster consume the PREVIOUSLY-read subtile
// while the next subtile's ds_reads are in flight (R6's overlap) with R9's
// proven staging invariants. ONE barrier per K-tile.
//
// iter kt (cur = kt%3; setA = frag(kt,k0), issued last iter tail):
//   LOADF(cur,k1)->setB        // 8 ds_read issued
//   sched_barrier(0)           // scheduler must not hoist MFMA above issues
//   DOMFMA(setA)               // compiler emits lgkmcnt(8): waits setA only
//                              //  (DS queue FIFO); setB flies under MFMA
//   s_waitcnt vmcnt(0)         // tile kt+1 landed (STAGE'd last iter tail,
//                              //  ~1 full iter ago > HBM latency)
//   s_barrier                  // certifies: tile kt+1 resident block-wide AND
//                              //  every wave consumed its buf(kt-1) reads
//                              //  (its MFMA(setB) of iter kt-1 precedes this)
//   STAGE(kt+2 -> (cur+2)%3)   // target = buf(kt-1): no pending readers ^
//   LOADF(cur+1,k0)->setA      // tile kt+1 certified by the barrier
//   sched_barrier(0)
//   DOMFMA(setB)               // lgkmcnt(8): waits setB; setA + DMA fly under
//
// vmcnt audit: STAGE issues 6/iter in the tail; the only vm-wait is vmcnt(0)
// mid-next-iter -> issue-to-wait gap ~= 1 iter (>2000 cyc > 900 HBM miss).
// LDS swizzle (T2, rule #21): phys chunk = logical chunk ^ (row&7), source
// pre-swizzled, reads XOR'd. R2/R4/R9 measured: conflicts = 0.
__global__ __launch_bounds__(512, 2) void gemm_bf16_bn(
    const ushort* __restrict__ A,   // [M][K] bf16 bits
    const ushort* __restrict__ B,   // [N][K] bf16 bits
    const float* __restrict__ alpha,
    const float* __restrict__ bias,
    float* __restrict__ C, int M, int N, int K) {
    __shared__ ushort As[3 * A_TILE];   // 96 KB
    __shared__ ushort Bs[3 * B_TILE];   // 48 KB

    const int tid  = threadIdx.x;
    const int wid  = tid >> 6;
    const int lane = tid & 63;

    // bijective XCD-aware block swizzle (m204)
    const int nwg  = (int)gridDim.x;
    const int orig = (int)blockIdx.x;
    const int q = nwg >> 3, rr = nwg & 7;
    const int xcd = orig & 7;
    const int swz = ((xcd < rr) ? xcd * (q + 1) : rr * (q + 1) + (xcd - rr) * q)
                    + (orig >> 3);
    const int nTilesN = N / BN;
    const int brow = (swz / nTilesN) * BM;
    const int bcol = (swz % nTilesN) * BN;

    // 8 waves = 4M x 2N, each owns a 64x64 output sub-tile
    const int wr = (wid >> 1) * 64;
    const int wc = (wid & 1) * 64;
    const int fr = lane & 15;
    const int hi = lane >> 4;

    // fragment LDS offsets (ushort units), loop-invariant, swizzled
    int offA[2][4], offB[2][4];
#pragma unroll
    for (int s = 0; s < 2; ++s) {
#pragma unroll
        for (int m = 0; m < 4; ++m) {
            int row = wr + m * 16 + fr;                  // row&7 == fr&7
            offA[s][m] = row * BK + (((s * 4 + hi) ^ (fr & 7)) * 8);
        }
#pragma unroll
        for (int n = 0; n < 4; ++n) {
            int row = wc + n * 16 + fr;
            offB[s][n] = row * BK + (((s * 4 + hi) ^ (fr & 7)) * 8);
        }
    }

    // staging: per 8 KB round (64 rows), thread t -> row t>>3, chunk t&7;
    // source chunk pre-swizzled: (lane&7) ^ (lane>>3)  [row&7 == lane>>3]
    const int srow = wid * 8 + (lane >> 3);
    const int scol = ((lane & 7) ^ (lane >> 3)) * 8;
    const ushort* aSrc = A + (size_t)(brow + srow) * K + scol;
    const ushort* bSrc = B + (size_t)(bcol + srow) * K + scol;
    const int stDst = wid * 512;   // wave-uniform LDS base (HW adds lane*16B)

    floatx4 acc[4][4];
#pragma unroll
    for (int m = 0; m < 4; ++m)
#pragma unroll
        for (int n = 0; n < 4; ++n) acc[m][n] = (floatx4)0.0f;

    auto STAGE = [&](int koff, int bufsel) {   // 6 gloads: A 4 rounds, B 2
        ushort* da = As + bufsel * A_TILE + stDst;
        ushort* db = Bs + bufsel * B_TILE + stDst;
        const ushort* sa = aSrc + koff;
        const ushort* sb = bSrc + koff;
        gload_lds16(sa,                   da);
        gload_lds16(sa + (size_t)64  * K, da + 4096);
        gload_lds16(sa + (size_t)128 * K, da + 8192);
        gload_lds16(sa + (size_t)192 * K, da + 12288);
        gload_lds16(sb,                   db);
        gload_lds16(sb + (size_t)64  * K, db + 4096);
    };

    auto LOADF = [&](int bufsel, int s, bf16x8 (&af)[4], bf16x8 (&bf)[4]) {
        const ushort* pA = As + bufsel * A_TILE;
        const ushort* pB = Bs + bufsel * B_TILE;
#pragma unroll
        for (int m = 0; m < 4; ++m) af[m] = *(const bf16x8*)(pA + offA[s][m]);
#pragma unroll
        for (int n = 0; n < 4; ++n) bf[n] = *(const bf16x8*)(pB + offB[s][n]);
    };

    auto DOMFMA = [&](bf16x8 (&af)[4], bf16x8 (&bf)[4]) {
        __builtin_amdgcn_s_setprio(1);
#pragma unroll
        for (int m = 0; m < 4; ++m)
#pragma unroll
            for (int n = 0; n < 4; ++n)
                acc[m][n] = __builtin_amdgcn_mfma_f32_16x16x32_bf16(
                    af[m], bf[n], acc[m][n], 0, 0, 0);
        __builtin_amdgcn_s_setprio(0);
    };

    const int nK = K / BK;   // caller guarantees >= 4

    bf16x8 afA[4], bfA[4], afB[4], bfB[4];

    STAGE(0, 0);                 // tile 0 -> buf 0
    STAGE(BK, 1);                // tile 1 -> buf 1
    asm volatile("s_waitcnt vmcnt(6)" ::: "memory");   // tile 0 landed (own)
    __builtin_amdgcn_s_barrier();                      // all waves' tile 0
    asm volatile("" ::: "memory");
    LOADF(0, 0, afA, bfA);                             // frag(0, k0)

    int cur = 0;
    for (int kt = 0; kt < nK; ++kt) {
        LOADF(cur, 1, afB, bfB);              // issue frag(kt,k1) reads
        __builtin_amdgcn_sched_barrier(0);    // issues stay above MFMA
        DOMFMA(afA, bfA);                     // k0; setB reads fly under it
        if (kt + 1 < nK) {
            asm volatile("s_waitcnt vmcnt(0)" ::: "memory");  // kt+1 landed
            __builtin_amdgcn_s_barrier();     // resident block-wide; buf(kt-1)
            asm volatile("" ::: "memory");    //  readers all done (see header)
            if (kt + 2 < nK) {
                int tgt = cur + 2; if (tgt >= 3) tgt -= 3;
                STAGE((kt + 2) * BK, tgt);    // 6 gloads into buf(kt-1)
            }
            int nxt = cur + 1; if (nxt >= 3) nxt -= 3;
            LOADF(nxt, 0, afA, bfA);          // frag(kt+1, k0)
            __builtin_amdgcn_sched_barrier(0);
            cur = nxt;
        }
        DOMFMA(afB, bfB);                     // k1; setA reads + DMA fly under
    }

    // epilogue: C/D layout col=lane&15, row=hi*4+j  [m89/m91 verified]
    float al[4], bi[4];
    const int ccol = bcol + wc + fr;
#pragma unroll
    for (int n = 0; n < 4; ++n) {
        al[n] = alpha[ccol + n * 16];
        bi[n] = bias[ccol + n * 16];
    }
    const int r0 = brow + wr + hi * 4;
#pragma unroll
    for (int m = 0; m < 4; ++m)
#pragma unroll
        for (int n = 0; n < 4; ++n)
#pragma unroll
            for (int j = 0; j < 4; ++j) {
                int row = r0 + m * 16 + j;
                int col = ccol + n * 16;
                C[(size_t)row * N + col] = acc[m][n][j] * al[n] + bi[n];
            }
}

// ---------------- safety fallback (fp32 vector, naive) ----------------------
__global__ void gemm_f32_naive(const float* __restrict__ A,
                               const float* __restrict__ B,
                               const float* __restrict__ scale,
                               const float* __restrict__ mean,
                               const float* __restrict__ var,
                               const float* __restrict__ gamma,
                               const float* __restrict__ beta,
                               float* __restrict__ C, int N, int K) {
    int o = blockIdx.x * blockDim.x + threadIdx.x;
    int b = blockIdx.y;
    if (o >= N) return;
    float s = 0.f;
    const float* a = A + (size_t)b * K;
    const float* w = B + (size_t)o * K;
    for (int k = 0; k < K; ++k) s += a[k] * w[k];
    float rs = rsqrtf(var[o] + EPS);
    float g = gamma[o] * rs;
    C[(size_t)b * N + o] = s * scale[o] * g + (beta[o] - mean[o] * g);
}

extern "C" void kernel_launch(void* const* d_in, const int* in_sizes, int n_in,
                              void* d_out, int out_size, void* d_ws, size_t ws_size,
                              hipStream_t stream) {
    const float* x     = (const float*)d_in[0];
    const float* w     = (const float*)d_in[1];
    const float* scale = (const float*)d_in[2];
    const float* mean  = (const float*)d_in[3];
    const float* var   = (const float*)d_in[4];
    const float* gamma = (const float*)d_in[5];
    const float* beta  = (const float*)d_in[6];
    float* out = (float*)d_out;

    const int OUT = in_sizes[2];
    const int IN  = in_sizes[1] / OUT;
    const int Bsz = in_sizes[0] / IN;

    const size_t xElems = (size_t)Bsz * IN;
    const size_t wElems = (size_t)OUT * IN;
    const size_t need = xElems * 2 + wElems * 2 + (size_t)OUT * 8;

    const bool tiled_ok = (Bsz % BM == 0) && (OUT % BN == 0) &&
                          (IN % BK == 0) && (IN / BK >= 4) &&
                          (ws_size >= need);

    if (!tiled_ok) {
        dim3 grid((OUT + 255) / 256, Bsz);
        gemm_f32_naive<<<grid, 256, 0, stream>>>(x, w, scale, mean, var, gamma,
                                                 beta, out, OUT, IN);
        return;
    }

    ushort* xb = (ushort*)d_ws;
    ushort* wb = xb + xElems;
    float* alpha = (float*)(wb + wElems);
    float* bias  = alpha + OUT;

    cvt_f32_to_bf16<<<2048, 256, 0, stream>>>(x, xb, (int)(xElems / 4));
    cvt_f32_to_bf16<<<2048, 256, 0, stream>>>(w, wb, (int)(wElems / 4));
    bn_fold<<<(OUT + 255) / 256, 256, 0, stream>>>(scale, mean, var, gamma, beta,
                                                   alpha, bias, OUT);

    dim3 grid((Bsz / BM) * (OUT / BN));
    gemm_bf16_bn<<<grid, 512, 0, stream>>>(xb, wb, alpha, bias, out, Bsz, OUT, IN);
}